// Round 1
// baseline (322.908 us; speedup 1.0000x reference)
//
#include <hip/hip_runtime.h>

#define BB 8
#define CC 256
#define HH 64
#define WW 64
#define RED 64
#define HW 4096   // HH*WW

// ---- tiny transpose: w_red [64,256] (o-major) -> wt [256,64] (c-major) ----
// Makes kern_gen's weight reads contiguous in the uniform index -> s_load_dwordxN.
__global__ __launch_bounds__(256) void transpose_wred(const float* __restrict__ w_red,
                                                      float* __restrict__ wt) {
    int idx = blockIdx.x * 256 + threadIdx.x;   // 64 blocks * 256 = 16384
    int o = idx >> 8, c = idx & 255;
    wt[c * RED + o] = w_red[idx];
}

// ---- depthwise 3x3 + bias, zero 'SAME' padding ----
// grid: (16 h-tiles, C, B), block 256 = 4 rows x 64 cols
__global__ __launch_bounds__(256) void dwconv3x3(const float* __restrict__ x,
                                                 const float* __restrict__ w,
                                                 const float* __restrict__ bias,
                                                 float* __restrict__ out) {
    const int t  = threadIdx.x;
    const int wx = t & 63;
    const int hy = (blockIdx.x << 2) + (t >> 6);
    const int c = blockIdx.y, b = blockIdx.z;
    const float* xp = x + ((size_t)(b * CC + c)) * HW;
    const float* wp = w + c * 9;                 // uniform per block -> scalar loads
    float acc = bias[c];
    #pragma unroll
    for (int ky = 0; ky < 3; ky++) {
        int h = hy + ky - 1;
        if (h < 0 || h >= HH) continue;
        const float* row = xp + h * WW;
        #pragma unroll
        for (int kx = 0; kx < 3; kx++) {
            int wc = wx + kx - 1;
            if (wc < 0 || wc >= WW) continue;
            acc += wp[ky * 3 + kx] * row[wc];
        }
    }
    out[((size_t)(b * CC + c)) * HW + hy * WW + wx] = acc;
}

// ---- involution kernel generation ----
// kern[b,j,hw] = b_span[j] + sum_o w_span[j,o] * relu(b_red[o] + sum_c wt[c,o]*x1[b,c,hw])
// block: 256 threads = 128 pixels x 2 channel-halves; 256 blocks cover 32768 pixels.
__global__ __launch_bounds__(256) void kern_gen(const float* __restrict__ x1,
                                                const float* __restrict__ wt,   // [256][64]
                                                const float* __restrict__ b_red,
                                                const float* __restrict__ w_span, // [9][64]
                                                const float* __restrict__ b_span,
                                                float* __restrict__ kern) {
    __shared__ float part[RED * 128];            // 32 KiB
    const int t    = threadIdx.x;
    const int px   = t & 127;
    const int half = t >> 7;
    const int pixel = blockIdx.x * 128 + px;
    const int b  = pixel >> 12;
    const int hw = pixel & 4095;
    const float* xp = x1 + (size_t)b * CC * HW + hw;

    float acc[RED];
    #pragma unroll
    for (int o = 0; o < RED; o++) acc[o] = 0.f;

    const int c0 = half * 128;
    for (int c = c0; c < c0 + 128; c++) {
        float xv = xp[(size_t)c * HW];           // coalesced across px
        const float* wrow = wt + c * RED;        // uniform, contiguous -> s_load
        #pragma unroll
        for (int o = 0; o < RED; o++) acc[o] += wrow[o] * xv;
    }

    if (half) {
        #pragma unroll
        for (int o = 0; o < RED; o++) part[o * 128 + px] = acc[o];  // conflict-free
    }
    __syncthreads();
    if (!half) {
        float kk[9];
        #pragma unroll
        for (int j = 0; j < 9; j++) kk[j] = b_span[j];
        #pragma unroll
        for (int o = 0; o < RED; o++) {
            float r = acc[o] + part[o * 128 + px] + b_red[o];
            r = fmaxf(r, 0.f);
            #pragma unroll
            for (int j = 0; j < 9; j++) kk[j] += w_span[j * RED + o] * r;
        }
        float* kp = kern + (size_t)b * 9 * HW + hw;
        #pragma unroll
        for (int j = 0; j < 9; j++) kp[j * HW] = kk[j];
    }
}

// ---- involution apply: y[b,c,h,w] = sum_k kern[b,k,h,w] * x1[b,c,h+dy,w+dx] ----
// grid: (16, C, B), block 256 = 4 rows x 64 cols
__global__ __launch_bounds__(256) void invol_apply(const float* __restrict__ x1,
                                                   const float* __restrict__ kern,
                                                   float* __restrict__ y) {
    const int t  = threadIdx.x;
    const int wx = t & 63;
    const int hy = (blockIdx.x << 2) + (t >> 6);
    const int c = blockIdx.y, b = blockIdx.z;
    const int hw = hy * WW + wx;
    const float* kp = kern + (size_t)b * 9 * HW + hw;
    float kv[9];
    #pragma unroll
    for (int j = 0; j < 9; j++) kv[j] = kp[j * HW];  // L2-resident (1.18 MB), coalesced
    const float* xp = x1 + ((size_t)(b * CC + c)) * HW;
    float acc = 0.f;
    #pragma unroll
    for (int ky = 0; ky < 3; ky++) {
        int h = hy + ky - 1;
        if (h < 0 || h >= HH) continue;
        const float* row = xp + h * WW;
        #pragma unroll
        for (int kx = 0; kx < 3; kx++) {
            int wc = wx + kx - 1;
            if (wc < 0 || wc >= WW) continue;
            acc += kv[ky * 3 + kx] * row[wc];
        }
    }
    y[((size_t)(b * CC + c)) * HW + hw] = acc;
}

extern "C" void kernel_launch(void* const* d_in, const int* in_sizes, int n_in,
                              void* d_out, int out_size, void* d_ws, size_t ws_size,
                              hipStream_t stream) {
    const float* x      = (const float*)d_in[0];
    const float* w_in   = (const float*)d_in[1];
    const float* b_in   = (const float*)d_in[2];
    const float* w_red  = (const float*)d_in[3];
    const float* b_red  = (const float*)d_in[4];
    const float* w_span = (const float*)d_in[5];
    const float* b_span = (const float*)d_in[6];
    const float* w_out  = (const float*)d_in[7];
    const float* b_out  = (const float*)d_in[8];
    float* out = (float*)d_out;

    float* ws   = (float*)d_ws;
    float* x1   = ws;                                  // 8*256*4096 = 8,388,608 f
    float* y    = x1 + (size_t)BB * CC * HW;           // 8,388,608 f
    float* kern = y  + (size_t)BB * CC * HW;           // 8*9*4096 = 294,912 f
    float* wt   = kern + (size_t)BB * 9 * HW;          // 16,384 f  (total ~68.3 MB)

    transpose_wred<<<64, 256, 0, stream>>>(w_red, wt);
    dwconv3x3<<<dim3(16, CC, BB), 256, 0, stream>>>(x, w_in, b_in, x1);
    kern_gen<<<256, 256, 0, stream>>>(x1, wt, b_red, w_span, b_span, kern);
    invol_apply<<<dim3(16, CC, BB), 256, 0, stream>>>(x1, kern, y);
    dwconv3x3<<<dim3(16, CC, BB), 256, 0, stream>>>(y, w_out, b_out, out);
}

// Round 2
// 284.456 us; speedup vs baseline: 1.1352x; 1.1352x over previous
//
#include <hip/hip_runtime.h>

#define BB 8
#define CC 256
#define HH 64
#define WW 64
#define RED 64
#define HW 4096   // HH*WW

// ---- tiny transpose: w_red [64,256] (o-major) -> wt [256,64] (c-major) ----
__global__ __launch_bounds__(256) void transpose_wred(const float* __restrict__ w_red,
                                                      float* __restrict__ wt) {
    int idx = blockIdx.x * 256 + threadIdx.x;   // 64 blocks * 256 = 16384
    int o = idx >> 8, c = idx & 255;
    wt[c * RED + o] = w_red[idx];
}

// ---- depthwise 3x3 + bias, zero 'SAME' padding ----
// grid: (16 h-tiles, C, B), block 256 = 4 rows x 64 cols
__global__ __launch_bounds__(256) void dwconv3x3(const float* __restrict__ x,
                                                 const float* __restrict__ w,
                                                 const float* __restrict__ bias,
                                                 float* __restrict__ out) {
    const int t  = threadIdx.x;
    const int wx = t & 63;
    const int hy = (blockIdx.x << 2) + (t >> 6);
    const int c = blockIdx.y, b = blockIdx.z;
    const float* xp = x + ((size_t)(b * CC + c)) * HW;
    const float* wp = w + c * 9;                 // uniform per block -> scalar loads
    float acc = bias[c];
    #pragma unroll
    for (int ky = 0; ky < 3; ky++) {
        int h = hy + ky - 1;
        if (h < 0 || h >= HH) continue;
        const float* row = xp + h * WW;
        #pragma unroll
        for (int kx = 0; kx < 3; kx++) {
            int wc = wx + kx - 1;
            if (wc < 0 || wc >= WW) continue;
            acc += wp[ky * 3 + kx] * row[wc];
        }
    }
    out[((size_t)(b * CC + c)) * HW + hy * WW + wx] = acc;
}

// ---- involution kernel generation, occupancy-oriented ----
// kern[b,j,hw] = b_span[j] + sum_o w_span[j,o] * relu(b_red[o] + sum_c wt[c,o]*x1[b,c,hw])
// block: 512 threads = 64 pixels x 8 o-groups (8 outputs each, acc[8] in VGPRs).
// Each wave is one o-group -> wt row is wave-uniform (s_load). 512 blocks -> 16 waves/CU.
__global__ __launch_bounds__(512) void kern_gen(const float* __restrict__ x1,
                                                const float* __restrict__ wt,     // [256][64]
                                                const float* __restrict__ b_red,
                                                const float* __restrict__ w_span, // [9][64]
                                                const float* __restrict__ b_span,
                                                float* __restrict__ kern) {
    __shared__ float part[8 * 9 * 64];           // 18 KiB
    const int t  = threadIdx.x;
    const int px = t & 63;
    const int og = t >> 6;                       // 0..7 (== wave id)
    const int o0 = og << 3;
    const int pixel = blockIdx.x * 64 + px;
    const int b  = pixel >> 12;
    const int hw = pixel & 4095;
    const float* xp = x1 + (size_t)b * CC * HW + hw;

    float acc[8];
    #pragma unroll
    for (int i = 0; i < 8; i++) acc[i] = 0.f;

    for (int c = 0; c < CC; c++) {
        float xv = xp[(size_t)c * HW];           // coalesced across px; L1/L2 reuse across og
        const float* wrow = wt + c * RED + o0;   // wave-uniform, contiguous -> s_load
        #pragma unroll
        for (int i = 0; i < 8; i++) acc[i] += wrow[i] * xv;
    }

    // relu + partial span contraction for this o-group
    float kk[9];
    #pragma unroll
    for (int j = 0; j < 9; j++) kk[j] = 0.f;
    #pragma unroll
    for (int i = 0; i < 8; i++) {
        float r = fmaxf(acc[i] + b_red[o0 + i], 0.f);
        #pragma unroll
        for (int j = 0; j < 9; j++) kk[j] += w_span[j * RED + o0 + i] * r;
    }

    #pragma unroll
    for (int j = 0; j < 9; j++) part[(og * 9 + j) * 64 + px] = kk[j];  // px stride 1: conflict-free
    __syncthreads();

    if (og == 0) {
        float* kp = kern + (size_t)b * 9 * HW + hw;
        #pragma unroll
        for (int j = 0; j < 9; j++) {
            float s = b_span[j];
            #pragma unroll
            for (int g = 0; g < 8; g++) s += part[(g * 9 + j) * 64 + px];
            kp[j * HW] = s;
        }
    }
}

// ---- involution apply: y[b,c,h,w] = sum_k kern[b,k,h,w] * x1[b,c,h+dy,w+dx] ----
// grid: (16, C, B), block 256 = 4 rows x 64 cols
__global__ __launch_bounds__(256) void invol_apply(const float* __restrict__ x1,
                                                   const float* __restrict__ kern,
                                                   float* __restrict__ y) {
    const int t  = threadIdx.x;
    const int wx = t & 63;
    const int hy = (blockIdx.x << 2) + (t >> 6);
    const int c = blockIdx.y, b = blockIdx.z;
    const int hw = hy * WW + wx;
    const float* kp = kern + (size_t)b * 9 * HW + hw;
    float kv[9];
    #pragma unroll
    for (int j = 0; j < 9; j++) kv[j] = kp[j * HW];  // L2-resident (1.18 MB), coalesced
    const float* xp = x1 + ((size_t)(b * CC + c)) * HW;
    float acc = 0.f;
    #pragma unroll
    for (int ky = 0; ky < 3; ky++) {
        int h = hy + ky - 1;
        if (h < 0 || h >= HH) continue;
        const float* row = xp + h * WW;
        #pragma unroll
        for (int kx = 0; kx < 3; kx++) {
            int wc = wx + kx - 1;
            if (wc < 0 || wc >= WW) continue;
            acc += kv[ky * 3 + kx] * row[wc];
        }
    }
    y[((size_t)(b * CC + c)) * HW + hw] = acc;
}

extern "C" void kernel_launch(void* const* d_in, const int* in_sizes, int n_in,
                              void* d_out, int out_size, void* d_ws, size_t ws_size,
                              hipStream_t stream) {
    const float* x      = (const float*)d_in[0];
    const float* w_in   = (const float*)d_in[1];
    const float* b_in   = (const float*)d_in[2];
    const float* w_red  = (const float*)d_in[3];
    const float* b_red  = (const float*)d_in[4];
    const float* w_span = (const float*)d_in[5];
    const float* b_span = (const float*)d_in[6];
    const float* w_out  = (const float*)d_in[7];
    const float* b_out  = (const float*)d_in[8];
    float* out = (float*)d_out;

    float* ws   = (float*)d_ws;
    float* x1   = ws;                                  // 8*256*4096 f
    float* y    = x1 + (size_t)BB * CC * HW;
    float* kern = y  + (size_t)BB * CC * HW;           // 8*9*4096 f
    float* wt   = kern + (size_t)BB * 9 * HW;          // 16,384 f

    transpose_wred<<<64, 256, 0, stream>>>(w_red, wt);
    dwconv3x3<<<dim3(16, CC, BB), 256, 0, stream>>>(x, w_in, b_in, x1);
    kern_gen<<<512, 512, 0, stream>>>(x1, wt, b_red, w_span, b_span, kern);
    invol_apply<<<dim3(16, CC, BB), 256, 0, stream>>>(x1, kern, y);
    dwconv3x3<<<dim3(16, CC, BB), 256, 0, stream>>>(y, w_out, b_out, out);
}

// Round 3
// 179.723 us; speedup vs baseline: 1.7967x; 1.5827x over previous
//
#include <hip/hip_runtime.h>

#define BB 8
#define CC 256
#define HH 64
#define WW 64
#define RED 64
#define HW 4096   // HH*WW

// ---- tiny transpose: w_red [64,256] (o-major) -> wt [256,64] (c-major) ----
__global__ __launch_bounds__(256) void transpose_wred(const float* __restrict__ w_red,
                                                      float* __restrict__ wt) {
    int idx = blockIdx.x * 256 + threadIdx.x;   // 64 blocks * 256 = 16384
    int o = idx >> 8, c = idx & 255;
    wt[c * RED + o] = w_red[idx];
}

// ---- depthwise 3x3 + bias, zero 'SAME' padding, 4 px/thread ----
// grid: (4, C, B), block 256 = 16 rows x 16 col-quads
__global__ __launch_bounds__(256) void dwconv3x3(const float* __restrict__ x,
                                                 const float* __restrict__ w,
                                                 const float* __restrict__ bias,
                                                 float* __restrict__ out) {
    const int t  = threadIdx.x;
    const int q  = t & 15;           // col-quad
    const int w0 = q << 2;
    const int h  = (blockIdx.x << 4) + (t >> 4);
    const int c = blockIdx.y, b = blockIdx.z;
    const float* xp = x + ((size_t)(b * CC + c)) * HW;
    const float* wp = w + c * 9;     // blockIdx-uniform -> s_load
    const float bb = bias[c];
    float4 acc = make_float4(bb, bb, bb, bb);
    #pragma unroll
    for (int ky = 0; ky < 3; ky++) {
        int hh = h + ky - 1;
        if (hh < 0 || hh >= HH) continue;
        const float* row = xp + hh * WW + w0;
        float4 v = *(const float4*)row;
        float lf = (w0 > 0)      ? row[-1] : 0.f;
        float rt = (w0 + 4 < WW) ? row[4]  : 0.f;
        float k0 = wp[ky * 3 + 0], k1 = wp[ky * 3 + 1], k2 = wp[ky * 3 + 2];
        acc.x = fmaf(k0, lf,  acc.x); acc.y = fmaf(k0, v.x, acc.y);
        acc.z = fmaf(k0, v.y, acc.z); acc.w = fmaf(k0, v.z, acc.w);
        acc.x = fmaf(k1, v.x, acc.x); acc.y = fmaf(k1, v.y, acc.y);
        acc.z = fmaf(k1, v.z, acc.z); acc.w = fmaf(k1, v.w, acc.w);
        acc.x = fmaf(k2, v.y, acc.x); acc.y = fmaf(k2, v.z, acc.y);
        acc.z = fmaf(k2, v.w, acc.z); acc.w = fmaf(k2, rt,  acc.w);
    }
    *(float4*)(out + ((size_t)(b * CC + c)) * HW + h * WW + w0) = acc;
}

// ---- involution kernel generation ----
// kern[b,j,hw] = b_span[j] + sum_o w_span[j,o] * relu(b_red[o] + sum_c wt[c,o]*x1[b,c,hw])
// 512 blocks x 512 threads = 64 px x 8 o-groups; weights via readfirstlane -> s_load.
__global__ __launch_bounds__(512) void kern_gen(const float* __restrict__ x1,
                                                const float* __restrict__ wt,     // [256][64]
                                                const float* __restrict__ b_red,
                                                const float* __restrict__ w_span, // [9][64]
                                                const float* __restrict__ b_span,
                                                float* __restrict__ kern) {
    __shared__ float part[8 * 9 * 64];           // 18 KiB
    const int t  = threadIdx.x;
    const int px = t & 63;
    const int o0 = __builtin_amdgcn_readfirstlane((t >> 6) << 3);  // wave-uniform -> SGPR
    const int og = t >> 6;
    const int pixel = blockIdx.x * 64 + px;
    const int b  = pixel >> 12;
    const int hw = pixel & 4095;
    const float* xp = x1 + (size_t)b * CC * HW + hw;
    const float* wp = wt + o0;                   // scalar-uniform base

    float acc[8];
    #pragma unroll
    for (int i = 0; i < 8; i++) acc[i] = 0.f;

    #pragma unroll 4
    for (int c = 0; c < CC; c++) {
        float xv = xp[(size_t)c * HW];           // coalesced across px
        const float* wrow = wp + c * RED;        // SGPR-uniform -> s_load_dwordx8
        #pragma unroll
        for (int i = 0; i < 8; i++) acc[i] = fmaf(wrow[i], xv, acc[i]);
    }

    // relu + partial span contraction for this o-group (all weights scalar)
    float kk[9];
    #pragma unroll
    for (int j = 0; j < 9; j++) kk[j] = 0.f;
    #pragma unroll
    for (int i = 0; i < 8; i++) {
        float r = fmaxf(acc[i] + b_red[o0 + i], 0.f);
        #pragma unroll
        for (int j = 0; j < 9; j++) kk[j] = fmaf(w_span[j * RED + o0 + i], r, kk[j]);
    }

    #pragma unroll
    for (int j = 0; j < 9; j++) part[(og * 9 + j) * 64 + px] = kk[j];
    __syncthreads();

    if (og == 0) {
        float* kp = kern + (size_t)b * 9 * HW + hw;
        #pragma unroll
        for (int j = 0; j < 9; j++) {
            float s = b_span[j];
            #pragma unroll
            for (int g = 0; g < 8; g++) s += part[(g * 9 + j) * 64 + px];
            kp[j * HW] = s;
        }
    }
}

// ---- involution apply, 4 px/thread ----
// grid: (4, C, B), block 256 = 16 rows x 16 col-quads
__global__ __launch_bounds__(256) void invol_apply(const float* __restrict__ x1,
                                                   const float* __restrict__ kern,
                                                   float* __restrict__ y) {
    const int t  = threadIdx.x;
    const int q  = t & 15;
    const int w0 = q << 2;
    const int h  = (blockIdx.x << 4) + (t >> 4);
    const int c = blockIdx.y, b = blockIdx.z;
    const int hw = h * WW + w0;
    const float* kp = kern + (size_t)b * 9 * HW + hw;
    float4 kv[9];
    #pragma unroll
    for (int j = 0; j < 9; j++) kv[j] = *(const float4*)(kp + j * HW);  // L2-resident
    const float* xp = x1 + ((size_t)(b * CC + c)) * HW;
    float4 acc = make_float4(0.f, 0.f, 0.f, 0.f);
    #pragma unroll
    for (int ky = 0; ky < 3; ky++) {
        int hh = h + ky - 1;
        if (hh < 0 || hh >= HH) continue;
        const float* row = xp + hh * WW + w0;
        float4 v = *(const float4*)row;
        float lf = (w0 > 0)      ? row[-1] : 0.f;
        float rt = (w0 + 4 < WW) ? row[4]  : 0.f;
        float4 k0 = kv[ky * 3 + 0], k1 = kv[ky * 3 + 1], k2 = kv[ky * 3 + 2];
        acc.x = fmaf(k0.x, lf,  acc.x); acc.y = fmaf(k0.y, v.x, acc.y);
        acc.z = fmaf(k0.z, v.y, acc.z); acc.w = fmaf(k0.w, v.z, acc.w);
        acc.x = fmaf(k1.x, v.x, acc.x); acc.y = fmaf(k1.y, v.y, acc.y);
        acc.z = fmaf(k1.z, v.z, acc.z); acc.w = fmaf(k1.w, v.w, acc.w);
        acc.x = fmaf(k2.x, v.y, acc.x); acc.y = fmaf(k2.y, v.z, acc.y);
        acc.z = fmaf(k2.z, v.w, acc.z); acc.w = fmaf(k2.w, rt,  acc.w);
    }
    *(float4*)(y + ((size_t)(b * CC + c)) * HW + hw) = acc;
}

extern "C" void kernel_launch(void* const* d_in, const int* in_sizes, int n_in,
                              void* d_out, int out_size, void* d_ws, size_t ws_size,
                              hipStream_t stream) {
    const float* x      = (const float*)d_in[0];
    const float* w_in   = (const float*)d_in[1];
    const float* b_in   = (const float*)d_in[2];
    const float* w_red  = (const float*)d_in[3];
    const float* b_red  = (const float*)d_in[4];
    const float* w_span = (const float*)d_in[5];
    const float* b_span = (const float*)d_in[6];
    const float* w_out  = (const float*)d_in[7];
    const float* b_out  = (const float*)d_in[8];
    float* out = (float*)d_out;

    float* ws   = (float*)d_ws;
    float* x1   = ws;                                  // 8*256*4096 f
    float* y    = x1 + (size_t)BB * CC * HW;
    float* kern = y  + (size_t)BB * CC * HW;           // 8*9*4096 f
    float* wt   = kern + (size_t)BB * 9 * HW;          // 16,384 f

    transpose_wred<<<64, 256, 0, stream>>>(w_red, wt);
    dwconv3x3<<<dim3(4, CC, BB), 256, 0, stream>>>(x, w_in, b_in, x1);
    kern_gen<<<512, 512, 0, stream>>>(x1, wt, b_red, w_span, b_span, kern);
    invol_apply<<<dim3(4, CC, BB), 256, 0, stream>>>(x1, kern, y);
    dwconv3x3<<<dim3(4, CC, BB), 256, 0, stream>>>(y, w_out, b_out, out);
}

// Round 4
// 157.806 us; speedup vs baseline: 2.0462x; 1.1389x over previous
//
#include <hip/hip_runtime.h>

#define BB 8
#define CC 256
#define HH 64
#define WW 64
#define RED 64
#define HW 4096   // HH*WW
#define LS 68     // LDS row stride: multiple of 4 (16B-aligned float4), 68%32=4 bank skew

// ---- tiny transpose: w_red [64,256] (o-major) -> wt [256,64] (c-major) ----
__global__ __launch_bounds__(256) void transpose_wred(const float* __restrict__ w_red,
                                                      float* __restrict__ wt) {
    int idx = blockIdx.x * 256 + threadIdx.x;   // 64 blocks * 256 = 16384
    int o = idx >> 8, c = idx & 255;
    wt[c * RED + o] = w_red[idx];
}

// ---- depthwise 3x3 + bias, zero 'SAME' padding, 4 px/thread ----
// grid: (4, C, B), block 256 = 16 rows x 16 col-quads
__global__ __launch_bounds__(256) void dwconv3x3(const float* __restrict__ x,
                                                 const float* __restrict__ w,
                                                 const float* __restrict__ bias,
                                                 float* __restrict__ out) {
    const int t  = threadIdx.x;
    const int q  = t & 15;           // col-quad
    const int w0 = q << 2;
    const int h  = (blockIdx.x << 4) + (t >> 4);
    const int c = blockIdx.y, b = blockIdx.z;
    const float* xp = x + ((size_t)(b * CC + c)) * HW;
    const float* wp = w + c * 9;     // block-uniform -> s_load
    const float bb = bias[c];
    float4 acc = make_float4(bb, bb, bb, bb);
    #pragma unroll
    for (int ky = 0; ky < 3; ky++) {
        int hh = h + ky - 1;
        if (hh < 0 || hh >= HH) continue;
        const float* row = xp + hh * WW + w0;
        float4 v = *(const float4*)row;
        float lf = (w0 > 0)      ? row[-1] : 0.f;
        float rt = (w0 + 4 < WW) ? row[4]  : 0.f;
        float k0 = wp[ky * 3 + 0], k1 = wp[ky * 3 + 1], k2 = wp[ky * 3 + 2];
        acc.x = fmaf(k0, lf,  acc.x); acc.y = fmaf(k0, v.x, acc.y);
        acc.z = fmaf(k0, v.y, acc.z); acc.w = fmaf(k0, v.z, acc.w);
        acc.x = fmaf(k1, v.x, acc.x); acc.y = fmaf(k1, v.y, acc.y);
        acc.z = fmaf(k1, v.z, acc.z); acc.w = fmaf(k1, v.w, acc.w);
        acc.x = fmaf(k2, v.y, acc.x); acc.y = fmaf(k2, v.z, acc.y);
        acc.z = fmaf(k2, v.w, acc.z); acc.w = fmaf(k2, rt,  acc.w);
    }
    *(float4*)(out + ((size_t)(b * CC + c)) * HW + h * WW + w0) = acc;
}

// ---- involution kernel generation ----
// kern[b,j,hw] = b_span[j] + sum_o w_span[j,o] * relu(b_red[o] + sum_c wt[c,o]*x1[b,c,hw])
// 512 blocks x 512 threads = 64 px x 8 o-groups; weights via readfirstlane -> s_load.
__global__ __launch_bounds__(512) void kern_gen(const float* __restrict__ x1,
                                                const float* __restrict__ wt,     // [256][64]
                                                const float* __restrict__ b_red,
                                                const float* __restrict__ w_span, // [9][64]
                                                const float* __restrict__ b_span,
                                                float* __restrict__ kern) {
    __shared__ float part[8 * 9 * 64];           // 18 KiB
    const int t  = threadIdx.x;
    const int px = t & 63;
    const int o0 = __builtin_amdgcn_readfirstlane((t >> 6) << 3);  // wave-uniform -> SGPR
    const int og = t >> 6;
    const int pixel = blockIdx.x * 64 + px;
    const int b  = pixel >> 12;
    const int hw = pixel & 4095;
    const float* xp = x1 + (size_t)b * CC * HW + hw;
    const float* wp = wt + o0;                   // scalar-uniform base

    float acc[8];
    #pragma unroll
    for (int i = 0; i < 8; i++) acc[i] = 0.f;

    #pragma unroll 4
    for (int c = 0; c < CC; c++) {
        float xv = xp[(size_t)c * HW];           // coalesced across px
        const float* wrow = wp + c * RED;        // SGPR-uniform -> s_load
        #pragma unroll
        for (int i = 0; i < 8; i++) acc[i] = fmaf(wrow[i], xv, acc[i]);
    }

    float kk[9];
    #pragma unroll
    for (int j = 0; j < 9; j++) kk[j] = 0.f;
    #pragma unroll
    for (int i = 0; i < 8; i++) {
        float r = fmaxf(acc[i] + b_red[o0 + i], 0.f);
        #pragma unroll
        for (int j = 0; j < 9; j++) kk[j] = fmaf(w_span[j * RED + o0 + i], r, kk[j]);
    }

    #pragma unroll
    for (int j = 0; j < 9; j++) part[(og * 9 + j) * 64 + px] = kk[j];
    __syncthreads();

    if (og == 0) {
        float* kp = kern + (size_t)b * 9 * HW + hw;
        #pragma unroll
        for (int j = 0; j < 9; j++) {
            float s = b_span[j];
            #pragma unroll
            for (int g = 0; g < 8; g++) s += part[(g * 9 + j) * 64 + px];
            kp[j * HW] = s;
        }
    }
}

// ---- fused involution-apply + dwconv3x3 (out) ----
// One block per (c,b) plane: 256 threads x 16 px. x1 plane staged in LDS,
// involution result kept in LDS, dwconv2 consumes it, writes final output.
// Saves the 67 MB y round-trip to HBM.
__global__ __launch_bounds__(256) void invol_dw(const float* __restrict__ x1,
                                                const float* __restrict__ kern,
                                                const float* __restrict__ w_out,
                                                const float* __restrict__ b_out,
                                                float* __restrict__ out) {
    __shared__ float xs[HH * LS];                // 17.4 KiB
    __shared__ float ys[HH * LS];                // 17.4 KiB
    const int t  = threadIdx.x;
    const int q  = t & 15;
    const int w0 = q << 2;
    const int r  = t >> 4;                       // 0..15
    const int c = blockIdx.x, b = blockIdx.y;
    const float* xp = x1 + ((size_t)(b * CC + c)) * HW;

    // stage x1 plane (4 rows/thread, coalesced float4)
    #pragma unroll
    for (int i = 0; i < 4; i++) {
        int h = r + (i << 4);
        *(float4*)&xs[h * LS + w0] = *(const float4*)(xp + h * WW + w0);
    }
    __syncthreads();

    // involution: y = sum_j kern[j] * shifted x1   (kern per-pixel, L2-resident)
    const float* kp = kern + (size_t)b * 9 * HW;
    #pragma unroll
    for (int i = 0; i < 4; i++) {
        int h  = r + (i << 4);
        int hw = h * WW + w0;
        float4 acc = make_float4(0.f, 0.f, 0.f, 0.f);
        #pragma unroll
        for (int ky = 0; ky < 3; ky++) {
            int hh = h + ky - 1;
            if (hh < 0 || hh >= HH) continue;
            const float* row = &xs[hh * LS + w0];
            float4 v = *(const float4*)row;
            float lf = (w0 > 0)      ? row[-1] : 0.f;
            float rt = (w0 + 4 < WW) ? row[4]  : 0.f;
            float4 k0 = *(const float4*)(kp + (ky * 3 + 0) * HW + hw);
            float4 k1 = *(const float4*)(kp + (ky * 3 + 1) * HW + hw);
            float4 k2 = *(const float4*)(kp + (ky * 3 + 2) * HW + hw);
            acc.x = fmaf(k0.x, lf,  acc.x); acc.y = fmaf(k0.y, v.x, acc.y);
            acc.z = fmaf(k0.z, v.y, acc.z); acc.w = fmaf(k0.w, v.z, acc.w);
            acc.x = fmaf(k1.x, v.x, acc.x); acc.y = fmaf(k1.y, v.y, acc.y);
            acc.z = fmaf(k1.z, v.z, acc.z); acc.w = fmaf(k1.w, v.w, acc.w);
            acc.x = fmaf(k2.x, v.y, acc.x); acc.y = fmaf(k2.y, v.z, acc.y);
            acc.z = fmaf(k2.w == k2.w ? k2.z : k2.z, v.w, acc.z); acc.w = fmaf(k2.w, rt, acc.w);
        }
        *(float4*)&ys[h * LS + w0] = acc;
    }
    __syncthreads();

    // dwconv2 from LDS y-plane
    const float* wp = w_out + c * 9;             // block-uniform -> s_load
    const float bb = b_out[c];
    float* op = out + ((size_t)(b * CC + c)) * HW;
    #pragma unroll
    for (int i = 0; i < 4; i++) {
        int h = r + (i << 4);
        float4 acc = make_float4(bb, bb, bb, bb);
        #pragma unroll
        for (int ky = 0; ky < 3; ky++) {
            int hh = h + ky - 1;
            if (hh < 0 || hh >= HH) continue;
            const float* row = &ys[hh * LS + w0];
            float4 v = *(const float4*)row;
            float lf = (w0 > 0)      ? row[-1] : 0.f;
            float rt = (w0 + 4 < WW) ? row[4]  : 0.f;
            float k0 = wp[ky * 3 + 0], k1 = wp[ky * 3 + 1], k2 = wp[ky * 3 + 2];
            acc.x = fmaf(k0, lf,  acc.x); acc.y = fmaf(k0, v.x, acc.y);
            acc.z = fmaf(k0, v.y, acc.z); acc.w = fmaf(k0, v.z, acc.w);
            acc.x = fmaf(k1, v.x, acc.x); acc.y = fmaf(k1, v.y, acc.y);
            acc.z = fmaf(k1, v.z, acc.z); acc.w = fmaf(k1, v.w, acc.w);
            acc.x = fmaf(k2, v.y, acc.x); acc.y = fmaf(k2, v.z, acc.y);
            acc.z = fmaf(k2, v.w, acc.z); acc.w = fmaf(k2, rt,  acc.w);
        }
        *(float4*)(op + h * WW + w0) = acc;
    }
}

extern "C" void kernel_launch(void* const* d_in, const int* in_sizes, int n_in,
                              void* d_out, int out_size, void* d_ws, size_t ws_size,
                              hipStream_t stream) {
    const float* x      = (const float*)d_in[0];
    const float* w_in   = (const float*)d_in[1];
    const float* b_in   = (const float*)d_in[2];
    const float* w_red  = (const float*)d_in[3];
    const float* b_red  = (const float*)d_in[4];
    const float* w_span = (const float*)d_in[5];
    const float* b_span = (const float*)d_in[6];
    const float* w_out  = (const float*)d_in[7];
    const float* b_out  = (const float*)d_in[8];
    float* out = (float*)d_out;

    float* ws   = (float*)d_ws;
    float* x1   = ws;                                  // 8*256*4096 f
    float* kern = x1 + (size_t)BB * CC * HW;           // 8*9*4096 f
    float* wt   = kern + (size_t)BB * 9 * HW;          // 16,384 f  (~35 MB total)

    transpose_wred<<<64, 256, 0, stream>>>(w_red, wt);
    dwconv3x3<<<dim3(4, CC, BB), 256, 0, stream>>>(x, w_in, b_in, x1);
    kern_gen<<<512, 512, 0, stream>>>(x1, wt, b_red, w_span, b_span, kern);
    invol_dw<<<dim3(CC, BB), 256, 0, stream>>>(x1, kern, w_out, b_out, out);
}

// Round 5
// 153.166 us; speedup vs baseline: 2.1082x; 1.0303x over previous
//
#include <hip/hip_runtime.h>

#define BB 8
#define CC 256
#define HH 64
#define WW 64
#define RED 64
#define HW 4096   // HH*WW
#define LS 68     // LDS row stride: multiple of 4 (16B-aligned float4), 68%32=4 bank skew

// ---- depthwise 3x3 + bias, zero 'SAME' padding, 4 px/thread ----
// grid: (5, C, B): bx<4 = conv h-tiles; bx==4,b==0 folds in the w_red transpose
// (wt[c][o] = w_red[o][c]) so it costs no extra launch.
__global__ __launch_bounds__(256) void dwconv1(const float* __restrict__ x,
                                               const float* __restrict__ w,
                                               const float* __restrict__ bias,
                                               float* __restrict__ out,
                                               const float* __restrict__ w_red,
                                               float* __restrict__ wt) {
    const int t = threadIdx.x;
    const int c = blockIdx.y, b = blockIdx.z;
    if (blockIdx.x == 4) {                       // transpose slice
        if (b == 0 && t < RED) wt[c * RED + t] = w_red[t * CC + c];
        return;
    }
    const int q  = t & 15;           // col-quad
    const int w0 = q << 2;
    const int h  = (blockIdx.x << 4) + (t >> 4);
    const float* xp = x + ((size_t)(b * CC + c)) * HW;
    const float* wp = w + c * 9;     // block-uniform -> s_load
    const float bb = bias[c];
    float4 acc = make_float4(bb, bb, bb, bb);
    #pragma unroll
    for (int ky = 0; ky < 3; ky++) {
        int hh = h + ky - 1;
        if (hh < 0 || hh >= HH) continue;
        const float* row = xp + hh * WW + w0;
        float4 v = *(const float4*)row;
        float lf = (w0 > 0)      ? row[-1] : 0.f;
        float rt = (w0 + 4 < WW) ? row[4]  : 0.f;
        float k0 = wp[ky * 3 + 0], k1 = wp[ky * 3 + 1], k2 = wp[ky * 3 + 2];
        acc.x = fmaf(k0, lf,  acc.x); acc.y = fmaf(k0, v.x, acc.y);
        acc.z = fmaf(k0, v.y, acc.z); acc.w = fmaf(k0, v.z, acc.w);
        acc.x = fmaf(k1, v.x, acc.x); acc.y = fmaf(k1, v.y, acc.y);
        acc.z = fmaf(k1, v.z, acc.z); acc.w = fmaf(k1, v.w, acc.w);
        acc.x = fmaf(k2, v.y, acc.x); acc.y = fmaf(k2, v.z, acc.y);
        acc.z = fmaf(k2, v.w, acc.z); acc.w = fmaf(k2, rt,  acc.w);
    }
    *(float4*)(out + ((size_t)(b * CC + c)) * HW + h * WW + w0) = acc;
}

// ---- involution kernel generation, LDS-staged ----
// kern[b,j,hw] = b_span[j] + sum_o w_span[j,o] * relu(b_red[o] + sum_c wt[c,o]*x1[b,c,hw])
// 512 blocks x 512 threads = 64 px x 8 o-groups. x staged in LDS per 64-c chunk
// (global line fetched once per block, not once per wave); weights all-scalar.
__global__ __launch_bounds__(512) void kern_gen(const float* __restrict__ x1,
                                                const float* __restrict__ wt,     // [256][64]
                                                const float* __restrict__ b_red,
                                                const float* __restrict__ w_span, // [9][64]
                                                const float* __restrict__ b_span,
                                                float* __restrict__ kern) {
    __shared__ float xs[64 * 64];                // 16 KiB: [c'][px]
    __shared__ float part[8 * 9 * 64];           // 18 KiB
    const int t  = threadIdx.x;
    const int px = t & 63;
    const int og = t >> 6;
    const int o0 = __builtin_amdgcn_readfirstlane(og << 3);  // wave-uniform -> SGPR
    const int pixel0 = blockIdx.x * 64;
    const int b   = pixel0 >> 12;
    const int hw0 = pixel0 & 4095;
    const float* xbase = x1 + (size_t)b * CC * HW + hw0;

    float acc[8];
    #pragma unroll
    for (int i = 0; i < 8; i++) acc[i] = 0.f;

    for (int c0 = 0; c0 < CC; c0 += 64) {
        // cooperative stage: 64 channels x 64 px, 8 floats/thread, coalesced
        #pragma unroll
        for (int k = 0; k < 8; k++) {
            int i  = t + k * 512;
            int cc = i >> 6, pp = i & 63;
            xs[i] = xbase[(size_t)(c0 + cc) * HW + pp];
        }
        __syncthreads();
        const float* wrow = wt + c0 * RED + o0;  // SGPR base
        #pragma unroll 8
        for (int c = 0; c < 64; c++) {
            float xv = xs[c * 64 + px];          // px stride 1: 2-way bank = free
            #pragma unroll
            for (int i = 0; i < 8; i++) acc[i] = fmaf(wrow[c * RED + i], xv, acc[i]);
        }
        __syncthreads();
    }

    float kk[9];
    #pragma unroll
    for (int j = 0; j < 9; j++) kk[j] = 0.f;
    #pragma unroll
    for (int i = 0; i < 8; i++) {
        float r = fmaxf(acc[i] + b_red[o0 + i], 0.f);
        #pragma unroll
        for (int j = 0; j < 9; j++) kk[j] = fmaf(w_span[j * RED + o0 + i], r, kk[j]);
    }

    #pragma unroll
    for (int j = 0; j < 9; j++) part[(og * 9 + j) * 64 + px] = kk[j];
    __syncthreads();

    if (og == 0) {
        float* kp = kern + (size_t)b * 9 * HW + hw0 + px;
        #pragma unroll
        for (int j = 0; j < 9; j++) {
            float s = b_span[j];
            #pragma unroll
            for (int g = 0; g < 8; g++) s += part[(g * 9 + j) * 64 + px];
            kp[j * HW] = s;
        }
    }
}

// ---- fused involution-apply + dwconv3x3 (out) ----
// One block per (c,b) plane: 256 threads x 16 px. x1 staged in LDS, involution
// result kept in LDS, dwconv2 consumes it. Saves the 67 MB y round-trip.
__global__ __launch_bounds__(256) void invol_dw(const float* __restrict__ x1,
                                                const float* __restrict__ kern,
                                                const float* __restrict__ w_out,
                                                const float* __restrict__ b_out,
                                                float* __restrict__ out) {
    __shared__ float xs[HH * LS];                // 17.4 KiB
    __shared__ float ys[HH * LS];                // 17.4 KiB
    const int t  = threadIdx.x;
    const int q  = t & 15;
    const int w0 = q << 2;
    const int r  = t >> 4;                       // 0..15
    const int c = blockIdx.x, b = blockIdx.y;
    const float* xp = x1 + ((size_t)(b * CC + c)) * HW;

    #pragma unroll
    for (int i = 0; i < 4; i++) {
        int h = r + (i << 4);
        *(float4*)&xs[h * LS + w0] = *(const float4*)(xp + h * WW + w0);
    }
    __syncthreads();

    const float* kp = kern + (size_t)b * 9 * HW;
    #pragma unroll
    for (int i = 0; i < 4; i++) {
        int h  = r + (i << 4);
        int hw = h * WW + w0;
        float4 acc = make_float4(0.f, 0.f, 0.f, 0.f);
        #pragma unroll
        for (int ky = 0; ky < 3; ky++) {
            int hh = h + ky - 1;
            if (hh < 0 || hh >= HH) continue;
            const float* row = &xs[hh * LS + w0];
            float4 v = *(const float4*)row;
            float lf = (w0 > 0)      ? row[-1] : 0.f;
            float rt = (w0 + 4 < WW) ? row[4]  : 0.f;
            float4 k0 = *(const float4*)(kp + (ky * 3 + 0) * HW + hw);
            float4 k1 = *(const float4*)(kp + (ky * 3 + 1) * HW + hw);
            float4 k2 = *(const float4*)(kp + (ky * 3 + 2) * HW + hw);
            acc.x = fmaf(k0.x, lf,  acc.x); acc.y = fmaf(k0.y, v.x, acc.y);
            acc.z = fmaf(k0.z, v.y, acc.z); acc.w = fmaf(k0.w, v.z, acc.w);
            acc.x = fmaf(k1.x, v.x, acc.x); acc.y = fmaf(k1.y, v.y, acc.y);
            acc.z = fmaf(k1.z, v.z, acc.z); acc.w = fmaf(k1.w, v.w, acc.w);
            acc.x = fmaf(k2.x, v.y, acc.x); acc.y = fmaf(k2.y, v.z, acc.y);
            acc.z = fmaf(k2.z, v.w, acc.z); acc.w = fmaf(k2.w, rt,  acc.w);
        }
        *(float4*)&ys[h * LS + w0] = acc;
    }
    __syncthreads();

    const float* wp = w_out + c * 9;             // block-uniform -> s_load
    const float bb = b_out[c];
    float* op = out + ((size_t)(b * CC + c)) * HW;
    #pragma unroll
    for (int i = 0; i < 4; i++) {
        int h = r + (i << 4);
        float4 acc = make_float4(bb, bb, bb, bb);
        #pragma unroll
        for (int ky = 0; ky < 3; ky++) {
            int hh = h + ky - 1;
            if (hh < 0 || hh >= HH) continue;
            const float* row = &ys[hh * LS + w0];
            float4 v = *(const float4*)row;
            float lf = (w0 > 0)      ? row[-1] : 0.f;
            float rt = (w0 + 4 < WW) ? row[4]  : 0.f;
            float k0 = wp[ky * 3 + 0], k1 = wp[ky * 3 + 1], k2 = wp[ky * 3 + 2];
            acc.x = fmaf(k0, lf,  acc.x); acc.y = fmaf(k0, v.x, acc.y);
            acc.z = fmaf(k0, v.y, acc.z); acc.w = fmaf(k0, v.z, acc.w);
            acc.x = fmaf(k1, v.x, acc.x); acc.y = fmaf(k1, v.y, acc.y);
            acc.z = fmaf(k1, v.z, acc.z); acc.w = fmaf(k1, v.w, acc.w);
            acc.x = fmaf(k2, v.y, acc.x); acc.y = fmaf(k2, v.z, acc.y);
            acc.z = fmaf(k2, v.w, acc.z); acc.w = fmaf(k2, rt,  acc.w);
        }
        *(float4*)(op + h * WW + w0) = acc;
    }
}

extern "C" void kernel_launch(void* const* d_in, const int* in_sizes, int n_in,
                              void* d_out, int out_size, void* d_ws, size_t ws_size,
                              hipStream_t stream) {
    const float* x      = (const float*)d_in[0];
    const float* w_in   = (const float*)d_in[1];
    const float* b_in   = (const float*)d_in[2];
    const float* w_red  = (const float*)d_in[3];
    const float* b_red  = (const float*)d_in[4];
    const float* w_span = (const float*)d_in[5];
    const float* b_span = (const float*)d_in[6];
    const float* w_out  = (const float*)d_in[7];
    const float* b_out  = (const float*)d_in[8];
    float* out = (float*)d_out;

    float* ws   = (float*)d_ws;
    float* x1   = ws;                                  // 8*256*4096 f
    float* kern = x1 + (size_t)BB * CC * HW;           // 8*9*4096 f
    float* wt   = kern + (size_t)BB * 9 * HW;          // 16,384 f  (~35 MB total)

    dwconv1<<<dim3(5, CC, BB), 256, 0, stream>>>(x, w_in, b_in, x1, w_red, wt);
    kern_gen<<<512, 512, 0, stream>>>(x1, wt, b_red, w_span, b_span, kern);
    invol_dw<<<dim3(CC, BB), 256, 0, stream>>>(x1, kern, w_out, b_out, out);
}

// Round 6
// 151.837 us; speedup vs baseline: 2.1267x; 1.0088x over previous
//
#include <hip/hip_runtime.h>

#define BB 8
#define CC 256
#define HH 64
#define WW 64
#define RED 64
#define HW 4096   // HH*WW
#define XS 68     // LDS row stride for channel-chunk tile (pad breaks row aliasing)
#define LS 68     // LDS row stride for image planes in invol_dw

// ---- fused dwconv1 + involution-kernel-generation ----
// One block per (row h, batch b): 512 threads. Per 64-channel chunk:
//   phase A: compute dwconv1 for 64 channels x this 64-px row from x (global,
//            L1/L2-cached halo), write to LDS xs AND to global x1.
//   phase B: kern_gen partial sums from LDS (8 o-groups x 8 outputs, weights
//            all through the scalar path -- w_red read o-major, no transpose).
// Epilogue: relu + span contraction + cross-o-group LDS reduction.
__global__ __launch_bounds__(512) void dw_kern(const float* __restrict__ x,
                                               const float* __restrict__ w_in,
                                               const float* __restrict__ b_in,
                                               const float* __restrict__ w_red,   // [64][256]
                                               const float* __restrict__ b_red,
                                               const float* __restrict__ w_span,  // [9][64]
                                               const float* __restrict__ b_span,
                                               float* __restrict__ x1,
                                               float* __restrict__ kern) {
    __shared__ float xs[64 * XS];                // 17.4 KiB: [c'][px]
    __shared__ float part[8 * 9 * 64];           // 18 KiB
    const int t  = threadIdx.x;
    const int h  = blockIdx.x;                   // 0..63 (block-uniform row)
    const int b  = blockIdx.y;
    const int px = t & 63;
    const int og = t >> 6;
    const int o0 = __builtin_amdgcn_readfirstlane(og << 3);  // -> SGPR
    // dwconv mapping: 16 col-quads x 32 channel-rows
    const int q  = t & 15;
    const int w0 = q << 2;
    const int cr = t >> 4;                       // 0..31

    float acc[8];
    #pragma unroll
    for (int i = 0; i < 8; i++) acc[i] = 0.f;

    for (int c0 = 0; c0 < CC; c0 += 64) {
        // ---- phase A: dwconv1 into xs + x1 (2 sub-iters of 32 channels) ----
        #pragma unroll
        for (int s = 0; s < 2; s++) {
            const int cl = s * 32 + cr;          // 0..63 within chunk
            const int cc = c0 + cl;              // global channel
            const float* xp = x + ((size_t)(b * CC + cc)) * HW;
            const float* wp = w_in + cc * 9;
            const float bb = b_in[cc];
            float4 a4 = make_float4(bb, bb, bb, bb);
            #pragma unroll
            for (int ky = 0; ky < 3; ky++) {
                int hh = h + ky - 1;
                if (hh < 0 || hh >= HH) continue;   // block-uniform: no divergence
                const float* row = xp + hh * WW + w0;
                float4 v = *(const float4*)row;
                float lf = (w0 > 0)      ? row[-1] : 0.f;
                float rt = (w0 + 4 < WW) ? row[4]  : 0.f;
                float k0 = wp[ky * 3 + 0], k1 = wp[ky * 3 + 1], k2 = wp[ky * 3 + 2];
                a4.x = fmaf(k0, lf,  a4.x); a4.y = fmaf(k0, v.x, a4.y);
                a4.z = fmaf(k0, v.y, a4.z); a4.w = fmaf(k0, v.z, a4.w);
                a4.x = fmaf(k1, v.x, a4.x); a4.y = fmaf(k1, v.y, a4.y);
                a4.z = fmaf(k1, v.z, a4.z); a4.w = fmaf(k1, v.w, a4.w);
                a4.x = fmaf(k2, v.y, a4.x); a4.y = fmaf(k2, v.z, a4.y);
                a4.z = fmaf(k2, v.w, a4.z); a4.w = fmaf(k2, rt,  a4.w);
            }
            *(float4*)&xs[cl * XS + w0] = a4;
            *(float4*)(x1 + ((size_t)(b * CC + cc)) * HW + h * WW + w0) = a4;
        }
        __syncthreads();
        // ---- phase B: reduce-GEMM from LDS, weights via scalar path ----
        const float* wr = w_red + o0 * CC + c0;  // SGPR-uniform base
        #pragma unroll 8
        for (int c = 0; c < 64; c++) {
            float xv = xs[c * XS + px];          // px stride 1: 2-way bank = free
            #pragma unroll
            for (int i = 0; i < 8; i++)
                acc[i] = fmaf(wr[i * CC + c], xv, acc[i]);
        }
        __syncthreads();
    }

    // ---- epilogue: relu + span contraction + o-group reduction ----
    float kk[9];
    #pragma unroll
    for (int j = 0; j < 9; j++) kk[j] = 0.f;
    #pragma unroll
    for (int i = 0; i < 8; i++) {
        float r = fmaxf(acc[i] + b_red[o0 + i], 0.f);
        #pragma unroll
        for (int j = 0; j < 9; j++) kk[j] = fmaf(w_span[j * RED + o0 + i], r, kk[j]);
    }
    #pragma unroll
    for (int j = 0; j < 9; j++) part[(og * 9 + j) * 64 + px] = kk[j];
    __syncthreads();
    if (og == 0) {
        float* kp = kern + (size_t)b * 9 * HW + h * WW + px;
        #pragma unroll
        for (int j = 0; j < 9; j++) {
            float s = b_span[j];
            #pragma unroll
            for (int g = 0; g < 8; g++) s += part[(g * 9 + j) * 64 + px];
            kp[j * HW] = s;
        }
    }
}

// ---- fused involution-apply + dwconv3x3 (out) ----
// One block per (c,b) plane: 256 threads x 16 px. x1 staged in LDS, involution
// result kept in LDS, dwconv2 consumes it. Saves the 67 MB y round-trip.
__global__ __launch_bounds__(256) void invol_dw(const float* __restrict__ x1,
                                                const float* __restrict__ kern,
                                                const float* __restrict__ w_out,
                                                const float* __restrict__ b_out,
                                                float* __restrict__ out) {
    __shared__ float xs[HH * LS];                // 17.4 KiB
    __shared__ float ys[HH * LS];                // 17.4 KiB
    const int t  = threadIdx.x;
    const int q  = t & 15;
    const int w0 = q << 2;
    const int r  = t >> 4;                       // 0..15
    const int c = blockIdx.x, b = blockIdx.y;
    const float* xp = x1 + ((size_t)(b * CC + c)) * HW;

    #pragma unroll
    for (int i = 0; i < 4; i++) {
        int h = r + (i << 4);
        *(float4*)&xs[h * LS + w0] = *(const float4*)(xp + h * WW + w0);
    }
    __syncthreads();

    const float* kp = kern + (size_t)b * 9 * HW;
    #pragma unroll
    for (int i = 0; i < 4; i++) {
        int h  = r + (i << 4);
        int hw = h * WW + w0;
        float4 acc = make_float4(0.f, 0.f, 0.f, 0.f);
        #pragma unroll
        for (int ky = 0; ky < 3; ky++) {
            int hh = h + ky - 1;
            if (hh < 0 || hh >= HH) continue;
            const float* row = &xs[hh * LS + w0];
            float4 v = *(const float4*)row;
            float lf = (w0 > 0)      ? row[-1] : 0.f;
            float rt = (w0 + 4 < WW) ? row[4]  : 0.f;
            float4 k0 = *(const float4*)(kp + (ky * 3 + 0) * HW + hw);
            float4 k1 = *(const float4*)(kp + (ky * 3 + 1) * HW + hw);
            float4 k2 = *(const float4*)(kp + (ky * 3 + 2) * HW + hw);
            acc.x = fmaf(k0.x, lf,  acc.x); acc.y = fmaf(k0.y, v.x, acc.y);
            acc.z = fmaf(k0.z, v.y, acc.z); acc.w = fmaf(k0.w, v.z, acc.w);
            acc.x = fmaf(k1.x, v.x, acc.x); acc.y = fmaf(k1.y, v.y, acc.y);
            acc.z = fmaf(k1.z, v.z, acc.z); acc.w = fmaf(k1.w, v.w, acc.w);
            acc.x = fmaf(k2.x, v.y, acc.x); acc.y = fmaf(k2.y, v.z, acc.y);
            acc.z = fmaf(k2.z, v.w, acc.z); acc.w = fmaf(k2.w, rt,  acc.w);
        }
        *(float4*)&ys[h * LS + w0] = acc;
    }
    __syncthreads();

    const float* wp = w_out + c * 9;             // block-uniform -> s_load
    const float bb = b_out[c];
    float* op = out + ((size_t)(b * CC + c)) * HW;
    #pragma unroll
    for (int i = 0; i < 4; i++) {
        int h = r + (i << 4);
        float4 acc = make_float4(bb, bb, bb, bb);
        #pragma unroll
        for (int ky = 0; ky < 3; ky++) {
            int hh = h + ky - 1;
            if (hh < 0 || hh >= HH) continue;
            const float* row = &ys[hh * LS + w0];
            float4 v = *(const float4*)row;
            float lf = (w0 > 0)      ? row[-1] : 0.f;
            float rt = (w0 + 4 < WW) ? row[4]  : 0.f;
            float k0 = wp[ky * 3 + 0], k1 = wp[ky * 3 + 1], k2 = wp[ky * 3 + 2];
            acc.x = fmaf(k0, lf,  acc.x); acc.y = fmaf(k0, v.x, acc.y);
            acc.z = fmaf(k0, v.y, acc.z); acc.w = fmaf(k0, v.z, acc.w);
            acc.x = fmaf(k1, v.x, acc.x); acc.y = fmaf(k1, v.y, acc.y);
            acc.z = fmaf(k1, v.z, acc.z); acc.w = fmaf(k1, v.w, acc.w);
            acc.x = fmaf(k2, v.y, acc.x); acc.y = fmaf(k2, v.z, acc.y);
            acc.z = fmaf(k2, v.w, acc.z); acc.w = fmaf(k2, rt,  acc.w);
        }
        *(float4*)(op + h * WW + w0) = acc;
    }
}

extern "C" void kernel_launch(void* const* d_in, const int* in_sizes, int n_in,
                              void* d_out, int out_size, void* d_ws, size_t ws_size,
                              hipStream_t stream) {
    const float* x      = (const float*)d_in[0];
    const float* w_in   = (const float*)d_in[1];
    const float* b_in   = (const float*)d_in[2];
    const float* w_red  = (const float*)d_in[3];
    const float* b_red  = (const float*)d_in[4];
    const float* w_span = (const float*)d_in[5];
    const float* b_span = (const float*)d_in[6];
    const float* w_out  = (const float*)d_in[7];
    const float* b_out  = (const float*)d_in[8];
    float* out = (float*)d_out;

    float* ws   = (float*)d_ws;
    float* x1   = ws;                                  // 8*256*4096 f
    float* kern = x1 + (size_t)BB * CC * HW;           // 8*9*4096 f

    dw_kern<<<dim3(HH, BB), 512, 0, stream>>>(x, w_in, b_in, w_red, b_red,
                                              w_span, b_span, x1, kern);
    invol_dw<<<dim3(CC, BB), 256, 0, stream>>>(x1, kern, w_out, b_out, out);
}

// Round 7
// 151.193 us; speedup vs baseline: 2.1357x; 1.0043x over previous
//
#include <hip/hip_runtime.h>

#define BB 8
#define CC 256
#define HH 64
#define WW 64
#define RED 64
#define HW 4096   // HH*WW
#define XS 68     // LDS row stride for channel-chunk tile
#define LS 68     // LDS row stride for image planes in invol_dw

// ---- fused dwconv1 + involution-kernel-generation, software-pipelined ----
// One block per (row h, batch b): 512 threads. Double-buffered LDS: phase A of
// chunk k+1 (dwconv from x -> LDS buf (k+1)&1 + global x1) is issued in the
// same barrier-free region as phase B of chunk k (reduce-GEMM from buf k&1),
// so global-load latency hides under the GEMM's FMA stream.
// h is XCD-swizzled so each XCD owns a contiguous 8-row band (halo L2 reuse).
__global__ __launch_bounds__(512) void dw_kern(const float* __restrict__ x,
                                               const float* __restrict__ w_in,
                                               const float* __restrict__ b_in,
                                               const float* __restrict__ w_red,   // [64][256]
                                               const float* __restrict__ b_red,
                                               const float* __restrict__ w_span,  // [9][64]
                                               const float* __restrict__ b_span,
                                               float* __restrict__ x1,
                                               float* __restrict__ kern) {
    __shared__ float xs[2][64 * XS];             // 2 x 17.4 KiB
    __shared__ float part[8 * 9 * 64];           // 18 KiB
    const int t  = threadIdx.x;
    const int bx = blockIdx.x;
    const int h  = ((bx & 7) << 3) | (bx >> 3);  // XCD band swizzle (perf only)
    const int b  = blockIdx.y;
    const int px = t & 63;
    const int og = t >> 6;
    const int o0 = __builtin_amdgcn_readfirstlane(og << 3);  // -> SGPR
    const int q  = t & 15;
    const int w0 = q << 2;
    const int cr = t >> 4;                       // 0..31

    float acc[8];
    #pragma unroll
    for (int i = 0; i < 8; i++) acc[i] = 0.f;

    // phase A for one 64-channel chunk -> LDS buf + global x1
    auto phaseA = [&](int c0, int buf) {
        #pragma unroll
        for (int s = 0; s < 2; s++) {
            const int cl = s * 32 + cr;          // 0..63 within chunk
            const int cc = c0 + cl;
            const float* xp = x + ((size_t)(b * CC + cc)) * HW;
            const float* wp = w_in + cc * 9;
            const float bb = b_in[cc];
            float4 a4 = make_float4(bb, bb, bb, bb);
            #pragma unroll
            for (int ky = 0; ky < 3; ky++) {
                int hh = h + ky - 1;
                if (hh < 0 || hh >= HH) continue;   // block-uniform
                const float* row = xp + hh * WW + w0;
                float4 v = *(const float4*)row;
                float lf = (w0 > 0)      ? row[-1] : 0.f;
                float rt = (w0 + 4 < WW) ? row[4]  : 0.f;
                float k0 = wp[ky * 3 + 0], k1 = wp[ky * 3 + 1], k2 = wp[ky * 3 + 2];
                a4.x = fmaf(k0, lf,  a4.x); a4.y = fmaf(k0, v.x, a4.y);
                a4.z = fmaf(k0, v.y, a4.z); a4.w = fmaf(k0, v.z, a4.w);
                a4.x = fmaf(k1, v.x, a4.x); a4.y = fmaf(k1, v.y, a4.y);
                a4.z = fmaf(k1, v.z, a4.z); a4.w = fmaf(k1, v.w, a4.w);
                a4.x = fmaf(k2, v.y, a4.x); a4.y = fmaf(k2, v.z, a4.y);
                a4.z = fmaf(k2, v.w, a4.z); a4.w = fmaf(k2, rt,  a4.w);
            }
            *(float4*)&xs[buf][cl * XS + w0] = a4;
            *(float4*)(x1 + ((size_t)(b * CC + cc)) * HW + h * WW + w0) = a4;
        }
    };

    phaseA(0, 0);
    __syncthreads();
    for (int k = 0; k < 4; k++) {
        if (k < 3) phaseA((k + 1) << 6, (k + 1) & 1);   // prefetch next chunk
        // phase B: reduce-GEMM from current buffer; weights via scalar path
        const float* wr = w_red + o0 * CC + (k << 6);   // SGPR-uniform base
        const float* xb = &xs[k & 1][0];
        #pragma unroll 8
        for (int c = 0; c < 64; c++) {
            float xv = xb[c * XS + px];          // stride-1 across lanes: conflict-free
            #pragma unroll
            for (int i = 0; i < 8; i++)
                acc[i] = fmaf(wr[i * CC + c], xv, acc[i]);
        }
        __syncthreads();
    }

    // epilogue: relu + span contraction + cross-o-group reduction
    float kk[9];
    #pragma unroll
    for (int j = 0; j < 9; j++) kk[j] = 0.f;
    #pragma unroll
    for (int i = 0; i < 8; i++) {
        float r = fmaxf(acc[i] + b_red[o0 + i], 0.f);
        #pragma unroll
        for (int j = 0; j < 9; j++) kk[j] = fmaf(w_span[j * RED + o0 + i], r, kk[j]);
    }
    #pragma unroll
    for (int j = 0; j < 9; j++) part[(og * 9 + j) * 64 + px] = kk[j];
    __syncthreads();
    if (og == 0) {
        float* kp = kern + (size_t)b * 9 * HW + h * WW + px;
        #pragma unroll
        for (int j = 0; j < 9; j++) {
            float s = b_span[j];
            #pragma unroll
            for (int g = 0; g < 8; g++) s += part[(g * 9 + j) * 64 + px];
            kp[j * HW] = s;
        }
    }
}

// ---- fused involution-apply + dwconv3x3 (out) ----
// One block per (c,b) plane: 256 threads x 16 px. x1 staged in LDS, involution
// result kept in LDS, dwconv2 consumes it. Saves the 67 MB y round-trip.
__global__ __launch_bounds__(256) void invol_dw(const float* __restrict__ x1,
                                                const float* __restrict__ kern,
                                                const float* __restrict__ w_out,
                                                const float* __restrict__ b_out,
                                                float* __restrict__ out) {
    __shared__ float xs[HH * LS];                // 17.4 KiB
    __shared__ float ys[HH * LS];                // 17.4 KiB
    const int t  = threadIdx.x;
    const int q  = t & 15;
    const int w0 = q << 2;
    const int r  = t >> 4;                       // 0..15
    const int c = blockIdx.x, b = blockIdx.y;
    const float* xp = x1 + ((size_t)(b * CC + c)) * HW;

    #pragma unroll
    for (int i = 0; i < 4; i++) {
        int h = r + (i << 4);
        *(float4*)&xs[h * LS + w0] = *(const float4*)(xp + h * WW + w0);
    }
    __syncthreads();

    const float* kp = kern + (size_t)b * 9 * HW;
    #pragma unroll
    for (int i = 0; i < 4; i++) {
        int h  = r + (i << 4);
        int hw = h * WW + w0;
        float4 acc = make_float4(0.f, 0.f, 0.f, 0.f);
        #pragma unroll
        for (int ky = 0; ky < 3; ky++) {
            int hh = h + ky - 1;
            if (hh < 0 || hh >= HH) continue;
            const float* row = &xs[hh * LS + w0];
            float4 v = *(const float4*)row;
            float lf = (w0 > 0)      ? row[-1] : 0.f;
            float rt = (w0 + 4 < WW) ? row[4]  : 0.f;
            float4 k0 = *(const float4*)(kp + (ky * 3 + 0) * HW + hw);
            float4 k1 = *(const float4*)(kp + (ky * 3 + 1) * HW + hw);
            float4 k2 = *(const float4*)(kp + (ky * 3 + 2) * HW + hw);
            acc.x = fmaf(k0.x, lf,  acc.x); acc.y = fmaf(k0.y, v.x, acc.y);
            acc.z = fmaf(k0.z, v.y, acc.z); acc.w = fmaf(k0.w, v.z, acc.w);
            acc.x = fmaf(k1.x, v.x, acc.x); acc.y = fmaf(k1.y, v.y, acc.y);
            acc.z = fmaf(k1.z, v.z, acc.z); acc.w = fmaf(k1.w, v.w, acc.w);
            acc.x = fmaf(k2.x, v.y, acc.x); acc.y = fmaf(k2.y, v.z, acc.y);
            acc.z = fmaf(k2.z, v.w, acc.z); acc.w = fmaf(k2.w, rt,  acc.w);
        }
        *(float4*)&ys[h * LS + w0] = acc;
    }
    __syncthreads();

    const float* wp = w_out + c * 9;             // block-uniform -> s_load
    const float bb = b_out[c];
    float* op = out + ((size_t)(b * CC + c)) * HW;
    #pragma unroll
    for (int i = 0; i < 4; i++) {
        int h = r + (i << 4);
        float4 acc = make_float4(bb, bb, bb, bb);
        #pragma unroll
        for (int ky = 0; ky < 3; ky++) {
            int hh = h + ky - 1;
            if (hh < 0 || hh >= HH) continue;
            const float* row = &ys[hh * LS + w0];
            float4 v = *(const float4*)row;
            float lf = (w0 > 0)      ? row[-1] : 0.f;
            float rt = (w0 + 4 < WW) ? row[4]  : 0.f;
            float k0 = wp[ky * 3 + 0], k1 = wp[ky * 3 + 1], k2 = wp[ky * 3 + 2];
            acc.x = fmaf(k0, lf,  acc.x); acc.y = fmaf(k0, v.x, acc.y);
            acc.z = fmaf(k0, v.y, acc.z); acc.w = fmaf(k0, v.z, acc.w);
            acc.x = fmaf(k1, v.x, acc.x); acc.y = fmaf(k1, v.y, acc.y);
            acc.z = fmaf(k1, v.z, acc.z); acc.w = fmaf(k1, v.w, acc.w);
            acc.x = fmaf(k2, v.y, acc.x); acc.y = fmaf(k2, v.z, acc.y);
            acc.z = fmaf(k2, v.w, acc.z); acc.w = fmaf(k2, rt,  acc.w);
        }
        *(float4*)(op + h * WW + w0) = acc;
    }
}

extern "C" void kernel_launch(void* const* d_in, const int* in_sizes, int n_in,
                              void* d_out, int out_size, void* d_ws, size_t ws_size,
                              hipStream_t stream) {
    const float* x      = (const float*)d_in[0];
    const float* w_in   = (const float*)d_in[1];
    const float* b_in   = (const float*)d_in[2];
    const float* w_red  = (const float*)d_in[3];
    const float* b_red  = (const float*)d_in[4];
    const float* w_span = (const float*)d_in[5];
    const float* b_span = (const float*)d_in[6];
    const float* w_out  = (const float*)d_in[7];
    const float* b_out  = (const float*)d_in[8];
    float* out = (float*)d_out;

    float* ws   = (float*)d_ws;
    float* x1   = ws;                                  // 8*256*4096 f
    float* kern = x1 + (size_t)BB * CC * HW;           // 8*9*4096 f

    dw_kern<<<dim3(HH, BB), 512, 0, stream>>>(x, w_in, b_in, w_red, b_red,
                                              w_span, b_span, x1, kern);
    invol_dw<<<dim3(CC, BB), 256, 0, stream>>>(x1, kern, w_out, b_out, out);
}